// Round 1
// baseline (288.131 us; speedup 1.0000x reference)
//
#include <hip/hip_runtime.h>
#include <hip/hip_bf16.h>
#include <stdint.h>

// Problem constants (B=4, L=4096, D=1024, K=3)
#define B_SZ   4
#define L_SEQ  4096
#define D_DIM  1024
#define M_TOT  (B_SZ * L_SEQ)   // 16384

typedef __bf16 bf16;
typedef __attribute__((ext_vector_type(8))) __bf16 bf16x8;
typedef __attribute__((ext_vector_type(4))) float   f32x4;

// ---------------------------------------------------------------------------
// Kernel 1: causal depthwise conv (K=3) + bf16 cast.
// Block = 256 threads covering all D (4 channels/thread). Each block owns one
// (batch, 32-long l-chunk). Sliding 3-row window in registers -> x read ~1x.
// ---------------------------------------------------------------------------
__global__ __launch_bounds__(256) void dw_bf16_kernel(
    const float* __restrict__ x, const float* __restrict__ w_dw,
    const float* __restrict__ b_dw, bf16* __restrict__ y) {
  const int t  = threadIdx.x;
  const int b  = blockIdx.x >> 7;     // / (L_SEQ/32 = 128)
  const int lc = blockIdx.x & 127;
  const int l0 = lc * 32;
  const int d0 = t * 4;

  float w0[4], w1[4], w2[4], bias[4];
#pragma unroll
  for (int c = 0; c < 4; ++c) {
    int d = d0 + c;
    w0[c] = w_dw[d * 3 + 0];
    w1[c] = w_dw[d * 3 + 1];
    w2[c] = w_dw[d * 3 + 2];
    bias[c] = b_dw[d];
  }

  const float* xb = x + (size_t)b * L_SEQ * D_DIM;
  bf16*        yb = y + (size_t)b * L_SEQ * D_DIM;

  float4 xm2 = make_float4(0.f, 0.f, 0.f, 0.f);
  float4 xm1 = make_float4(0.f, 0.f, 0.f, 0.f);
  if (l0 >= 2) xm2 = *(const float4*)(xb + (size_t)(l0 - 2) * D_DIM + d0);
  if (l0 >= 1) xm1 = *(const float4*)(xb + (size_t)(l0 - 1) * D_DIM + d0);

  for (int i = 0; i < 32; ++i) {
    int l = l0 + i;
    float4 xc = *(const float4*)(xb + (size_t)l * D_DIM + d0);
    float a0 = fmaf(xm2.x, w0[0], fmaf(xm1.x, w1[0], fmaf(xc.x, w2[0], bias[0])));
    float a1 = fmaf(xm2.y, w0[1], fmaf(xm1.y, w1[1], fmaf(xc.y, w2[1], bias[1])));
    float a2 = fmaf(xm2.z, w0[2], fmaf(xm1.z, w1[2], fmaf(xc.z, w2[2], bias[2])));
    float a3 = fmaf(xm2.w, w0[3], fmaf(xm1.w, w1[3], fmaf(xc.w, w2[3], bias[3])));
    union { bf16 h[4]; int2 v; } o;
    o.h[0] = (bf16)a0; o.h[1] = (bf16)a1; o.h[2] = (bf16)a2; o.h[3] = (bf16)a3;
    *(int2*)(yb + (size_t)l * D_DIM + d0) = o.v;
    xm2 = xm1;
    xm1 = xc;
  }
}

// ---------------------------------------------------------------------------
// Kernel 2: w_pw fp32 -> bf16 (1024x1024)
// ---------------------------------------------------------------------------
__global__ __launch_bounds__(256) void cvt_bf16_kernel(
    const float* __restrict__ w, bf16* __restrict__ o) {
  int i = (blockIdx.x * 256 + threadIdx.x) * 8;
  float4 a = *(const float4*)(w + i);
  float4 b = *(const float4*)(w + i + 4);
  union { bf16 h[8]; int4 v; } r;
  r.h[0] = (bf16)a.x; r.h[1] = (bf16)a.y; r.h[2] = (bf16)a.z; r.h[3] = (bf16)a.w;
  r.h[4] = (bf16)b.x; r.h[5] = (bf16)b.y; r.h[6] = (bf16)b.z; r.h[7] = (bf16)b.w;
  *(int4*)(o + i) = r.v;
}

// ---------------------------------------------------------------------------
// Kernel 3: GEMM  out[m][n] = sum_k y[m][k] * w_pw[n][k] + b_pw[n]
// M=16384, N=1024, K=1024. BM=BN=128, BK=64. 256 threads = 4 waves (2x2),
// each wave: 4x4 grid of 16x16x32 bf16 MFMA tiles (64x64 per wave).
// LDS: XOR-swizzled chunk layout (16B chunks, chunk' = chunk ^ (row&7)) ->
// fragment ds_read_b128 lands 2-way on banks (free).
// ---------------------------------------------------------------------------
#define BM 128
#define BN 128
#define BK 64

__global__ __launch_bounds__(256) void gemm_bt_kernel(
    const bf16* __restrict__ A,   // M x K row-major (y, bf16)
    const bf16* __restrict__ Bm,  // N x K row-major (w_pw, bf16)
    const float* __restrict__ bias, float* __restrict__ C) {
  __shared__ bf16 Asm[BM * BK];
  __shared__ bf16 Bsm[BN * BK];

  const int t    = threadIdx.x;
  const int m0   = blockIdx.x * BM;
  const int n0   = blockIdx.y * BN;
  const int lane = t & 63;
  const int wv   = t >> 6;
  const int wm   = (wv >> 1) * 64;
  const int wn   = (wv & 1) * 64;
  const int lrow = lane & 15;
  const int q    = lane >> 4;

  f32x4 acc[4][4] = {};

  for (int k0 = 0; k0 < D_DIM; k0 += BK) {
    // --- stage: global -> regs (4 x 16B chunks each for A and B) ---
    int4 ra[4], rb[4];
#pragma unroll
    for (int i = 0; i < 4; ++i) {
      int s   = i * 256 + t;       // LDS slot (16B units)
      int row = s >> 3;            // tile row
      int gc  = (s & 7) ^ (row & 7);  // global 16B chunk within row (unswizzle)
      ra[i] = *(const int4*)(A  + (size_t)(m0 + row) * D_DIM + k0 + gc * 8);
      rb[i] = *(const int4*)(Bm + (size_t)(n0 + row) * D_DIM + k0 + gc * 8);
    }
    __syncthreads();   // previous iter's LDS reads complete
#pragma unroll
    for (int i = 0; i < 4; ++i) {
      int s = i * 256 + t;
      *(int4*)((char*)Asm + (size_t)s * 16) = ra[i];
      *(int4*)((char*)Bsm + (size_t)s * 16) = rb[i];
    }
    __syncthreads();

    // --- compute: 2 x (8 frag loads + 16 MFMA) ---
#pragma unroll
    for (int kk = 0; kk < 2; ++kk) {
      bf16x8 af[4], bfr[4];
#pragma unroll
      for (int i = 0; i < 4; ++i) {
        int mrow = wm + i * 16 + lrow;
        int ck   = (kk * 4 + q) ^ (mrow & 7);
        af[i] = *(const bf16x8*)((const char*)Asm + (size_t)mrow * (BK * 2) + ck * 16);
        int nrow = wn + i * 16 + lrow;
        int ckb  = (kk * 4 + q) ^ (nrow & 7);
        bfr[i] = *(const bf16x8*)((const char*)Bsm + (size_t)nrow * (BK * 2) + ckb * 16);
      }
#pragma unroll
      for (int i = 0; i < 4; ++i)
#pragma unroll
        for (int j = 0; j < 4; ++j)
          acc[i][j] = __builtin_amdgcn_mfma_f32_16x16x32_bf16(af[i], bfr[j], acc[i][j], 0, 0, 0);
    }
  }

  // --- epilogue: C/D layout col = lane&15 (n), row = q*4 + reg (m) ---
#pragma unroll
  for (int j = 0; j < 4; ++j) {
    int n = n0 + wn + j * 16 + lrow;
    float bv = bias[n];
#pragma unroll
    for (int i = 0; i < 4; ++i) {
      int mb = m0 + wm + i * 16 + q * 4;
#pragma unroll
      for (int r = 0; r < 4; ++r)
        C[(size_t)(mb + r) * D_DIM + n] = acc[i][j][r] + bv;
    }
  }
}

// ---------------------------------------------------------------------------
// Fallback (only if workspace is too small): correct but slow fp32 path.
// ---------------------------------------------------------------------------
__global__ __launch_bounds__(256) void fallback_kernel(
    const float* __restrict__ x, const float* __restrict__ w_dw,
    const float* __restrict__ b_dw, const float* __restrict__ w_pw,
    const float* __restrict__ b_pw, float* __restrict__ out) {
  __shared__ float ys[D_DIM];
  const int m = blockIdx.x;
  const int l = m & (L_SEQ - 1);
  const int t = threadIdx.x;
  const float* xr = x + (size_t)m * D_DIM;
#pragma unroll
  for (int c = 0; c < 4; ++c) {
    int d = t + c * 256;
    float a = fmaf(xr[d], w_dw[d * 3 + 2], b_dw[d]);
    if (l >= 1) a = fmaf(xr[d - D_DIM], w_dw[d * 3 + 1], a);
    if (l >= 2) a = fmaf(xr[d - 2 * D_DIM], w_dw[d * 3 + 0], a);
    ys[d] = a;
  }
  __syncthreads();
#pragma unroll
  for (int c = 0; c < 4; ++c) {
    int e = t + c * 256;
    const float* wr = w_pw + (size_t)e * D_DIM;
    float a = b_pw[e];
    for (int d = 0; d < D_DIM; ++d) a = fmaf(ys[d], wr[d], a);
    out[(size_t)m * D_DIM + e] = a;
  }
}

extern "C" void kernel_launch(void* const* d_in, const int* in_sizes, int n_in,
                              void* d_out, int out_size, void* d_ws, size_t ws_size,
                              hipStream_t stream) {
  (void)in_sizes; (void)n_in; (void)out_size;
  const float* x    = (const float*)d_in[0];
  const float* w_dw = (const float*)d_in[1];
  const float* b_dw = (const float*)d_in[2];
  const float* w_pw = (const float*)d_in[3];
  const float* b_pw = (const float*)d_in[4];
  float* out = (float*)d_out;

  const size_t y_elems = (size_t)M_TOT * D_DIM;          // 16M bf16 = 32 MB
  const size_t w_elems = (size_t)D_DIM * D_DIM;          // 1M bf16  =  2 MB
  const size_t need = (y_elems + w_elems) * sizeof(bf16);

  if (ws_size >= need) {
    bf16* y    = (bf16*)d_ws;
    bf16* wpwb = (bf16*)d_ws + y_elems;
    dw_bf16_kernel<<<B_SZ * (L_SEQ / 32), 256, 0, stream>>>(x, w_dw, b_dw, y);
    cvt_bf16_kernel<<<(D_DIM * D_DIM / 8) / 256, 256, 0, stream>>>(w_pw, wpwb);
    dim3 grid(M_TOT / BM, D_DIM / BN);
    gemm_bt_kernel<<<grid, 256, 0, stream>>>(y, wpwb, b_pw, out);
  } else {
    fallback_kernel<<<M_TOT, 256, 0, stream>>>(x, w_dw, b_dw, w_pw, b_pw, out);
  }
}

// Round 2
// 171.870 us; speedup vs baseline: 1.6764x; 1.6764x over previous
//
#include <hip/hip_runtime.h>
#include <hip/hip_bf16.h>
#include <stdint.h>

// Problem constants (B=4, L=4096, D=1024, K=3)
#define B_SZ   4
#define L_SEQ  4096
#define D_DIM  1024
#define M_TOT  (B_SZ * L_SEQ)   // 16384

typedef __bf16 bf16;
typedef __attribute__((ext_vector_type(8))) __bf16 bf16x8;
typedef __attribute__((ext_vector_type(4))) float   f32x4;

#define GLOAD_LDS16(g, l)                                                     \
  __builtin_amdgcn_global_load_lds(                                           \
      (const __attribute__((address_space(1))) void*)(g),                     \
      (__attribute__((address_space(3))) void*)(l), 16, 0, 0)

// ---------------------------------------------------------------------------
// Kernel 1: causal depthwise conv (K=3) + bf16 cast.
// 16 l-steps per block -> 1024 blocks (4/CU) for latency hiding.
// ---------------------------------------------------------------------------
__global__ __launch_bounds__(256) void dw_bf16_kernel(
    const float* __restrict__ x, const float* __restrict__ w_dw,
    const float* __restrict__ b_dw, bf16* __restrict__ y) {
  const int t  = threadIdx.x;
  const int b  = blockIdx.x >> 8;     // / (L_SEQ/16 = 256)
  const int lc = blockIdx.x & 255;
  const int l0 = lc * 16;
  const int d0 = t * 4;

  float w0[4], w1[4], w2[4], bias[4];
#pragma unroll
  for (int c = 0; c < 4; ++c) {
    int d = d0 + c;
    w0[c] = w_dw[d * 3 + 0];
    w1[c] = w_dw[d * 3 + 1];
    w2[c] = w_dw[d * 3 + 2];
    bias[c] = b_dw[d];
  }

  const float* xb = x + (size_t)b * L_SEQ * D_DIM;
  bf16*        yb = y + (size_t)b * L_SEQ * D_DIM;

  float4 xm2 = make_float4(0.f, 0.f, 0.f, 0.f);
  float4 xm1 = make_float4(0.f, 0.f, 0.f, 0.f);
  if (l0 >= 2) xm2 = *(const float4*)(xb + (size_t)(l0 - 2) * D_DIM + d0);
  if (l0 >= 1) xm1 = *(const float4*)(xb + (size_t)(l0 - 1) * D_DIM + d0);

#pragma unroll 4
  for (int i = 0; i < 16; ++i) {
    int l = l0 + i;
    float4 xc = *(const float4*)(xb + (size_t)l * D_DIM + d0);
    float a0 = fmaf(xm2.x, w0[0], fmaf(xm1.x, w1[0], fmaf(xc.x, w2[0], bias[0])));
    float a1 = fmaf(xm2.y, w0[1], fmaf(xm1.y, w1[1], fmaf(xc.y, w2[1], bias[1])));
    float a2 = fmaf(xm2.z, w0[2], fmaf(xm1.z, w1[2], fmaf(xc.z, w2[2], bias[2])));
    float a3 = fmaf(xm2.w, w0[3], fmaf(xm1.w, w1[3], fmaf(xc.w, w2[3], bias[3])));
    union { bf16 h[4]; int2 v; } o;
    o.h[0] = (bf16)a0; o.h[1] = (bf16)a1; o.h[2] = (bf16)a2; o.h[3] = (bf16)a3;
    *(int2*)(yb + (size_t)l * D_DIM + d0) = o.v;
    xm2 = xm1;
    xm1 = xc;
  }
}

// ---------------------------------------------------------------------------
// Kernel 2: w_pw fp32 -> bf16 (1024x1024)
// ---------------------------------------------------------------------------
__global__ __launch_bounds__(256) void cvt_bf16_kernel(
    const float* __restrict__ w, bf16* __restrict__ o) {
  int i = (blockIdx.x * 256 + threadIdx.x) * 8;
  float4 a = *(const float4*)(w + i);
  float4 b = *(const float4*)(w + i + 4);
  union { bf16 h[8]; int4 v; } r;
  r.h[0] = (bf16)a.x; r.h[1] = (bf16)a.y; r.h[2] = (bf16)a.z; r.h[3] = (bf16)a.w;
  r.h[4] = (bf16)b.x; r.h[5] = (bf16)b.y; r.h[6] = (bf16)b.z; r.h[7] = (bf16)b.w;
  *(int4*)(o + i) = r.v;
}

// ---------------------------------------------------------------------------
// Kernel 3: GEMM  out[m][n] = sum_k y[m][k] * w_pw[n][k] + b_pw[n]
// M=16384, N=1024, K=1024. BM=BN=128, BK=64. 256 threads = 4 waves (2x2),
// each wave 64x64 via 4x4 grid of 16x16x32 bf16 MFMA.
// Staging: global_load_lds width=16 (async DMA, no VGPR round-trip).
//   LDS slot s = i*256 + t = wave-uniform base (i*256+wv*64) + lane (HW adds
//   lane*16). Global chunk XOR-swizzled: gc=(s&7)^(row&7) so fragment
//   ds_read_b128 is conflict-free (verified 0 conflicts in round 1).
// Epilogue: per-wave LDS transpose -> float4 stores, 256B contiguous/row.
// ---------------------------------------------------------------------------
#define BM 128
#define BN 128
#define BK 64
#define EP_ROWP 68   // fp32 per padded epilogue row (272B, 16B-aligned)

__global__ __launch_bounds__(256) void gemm_bt_kernel(
    const bf16* __restrict__ A,   // M x K row-major (y, bf16)
    const bf16* __restrict__ Bm,  // N x K row-major (w_pw, bf16)
    const float* __restrict__ bias, float* __restrict__ C) {
  __shared__ __align__(16) char smem[32768];
  bf16* Asm = (bf16*)smem;               // 16 KB
  bf16* Bsm = (bf16*)(smem + 16384);     // 16 KB

  const int t    = threadIdx.x;
  const int m0   = blockIdx.x * BM;
  const int n0   = blockIdx.y * BN;
  const int lane = t & 63;
  const int wv   = t >> 6;
  const int wm   = (wv >> 1) * 64;
  const int wn   = (wv & 1) * 64;
  const int lrow = lane & 15;
  const int q    = lane >> 4;

  f32x4 acc[4][4] = {};

  // Precompute per-lane global row/chunk for the 4 staging slots.
  int srow[4], sgc[4];
#pragma unroll
  for (int i = 0; i < 4; ++i) {
    int s   = i * 256 + t;
    srow[i] = s >> 3;
    sgc[i]  = (s & 7) ^ (srow[i] & 7);
  }

  for (int k0 = 0; k0 < D_DIM; k0 += BK) {
    __syncthreads();   // previous tile's LDS reads complete
#pragma unroll
    for (int i = 0; i < 4; ++i) {
      unsigned lds_off = (unsigned)(i * 4096 + wv * 1024);  // wave-uniform
      const bf16* ga = A  + (size_t)(m0 + srow[i]) * D_DIM + k0 + sgc[i] * 8;
      const bf16* gb = Bm + (size_t)(n0 + srow[i]) * D_DIM + k0 + sgc[i] * 8;
      GLOAD_LDS16(ga, (char*)Asm + lds_off);
      GLOAD_LDS16(gb, (char*)Bsm + lds_off);
    }
    __syncthreads();   // drains vmcnt -> tiles visible

#pragma unroll
    for (int kk = 0; kk < 2; ++kk) {
      bf16x8 af[4], bfr[4];
#pragma unroll
      for (int i = 0; i < 4; ++i) {
        int mrow = wm + i * 16 + lrow;
        int ck   = (kk * 4 + q) ^ (mrow & 7);
        af[i] = *(const bf16x8*)((const char*)Asm + (size_t)mrow * (BK * 2) + ck * 16);
        int nrow = wn + i * 16 + lrow;
        int ckb  = (kk * 4 + q) ^ (nrow & 7);
        bfr[i] = *(const bf16x8*)((const char*)Bsm + (size_t)nrow * (BK * 2) + ckb * 16);
      }
#pragma unroll
      for (int i = 0; i < 4; ++i)
#pragma unroll
        for (int j = 0; j < 4; ++j)
          acc[i][j] = __builtin_amdgcn_mfma_f32_16x16x32_bf16(af[i], bfr[j], acc[i][j], 0, 0, 0);
    }
  }

  // --- epilogue: per-wave LDS transpose, then coalesced float4 stores ---
  __syncthreads();   // all waves done reading Asm/Bsm
  float* ep = (float*)smem + (size_t)wv * (16 * EP_ROWP);  // private 4.25KB/wave

  float bvj[4];
#pragma unroll
  for (int j = 0; j < 4; ++j) bvj[j] = bias[n0 + wn + j * 16 + lrow];

#pragma unroll
  for (int i = 0; i < 4; ++i) {
    // write: C/D layout col(n)=lrow (+j*16), row(m)=q*4+r
#pragma unroll
    for (int j = 0; j < 4; ++j)
#pragma unroll
      for (int r = 0; r < 4; ++r)
        ep[(q * 4 + r) * EP_ROWP + j * 16 + lrow] = acc[i][j][r] + bvj[j];
    // read back row-major + store (wave-private region; in-wave DS ordering)
#pragma unroll
    for (int it = 0; it < 4; ++it) {
      int flat = it * 64 + lane;
      int row  = flat >> 4;          // 0..15 (m within chunk)
      int c4   = flat & 15;          // float4 index within 64-float row
      float4 v = *(const float4*)(ep + row * EP_ROWP + c4 * 4);
      int gm = m0 + wm + i * 16 + row;
      int gn = n0 + wn + c4 * 4;
      *(float4*)(C + (size_t)gm * D_DIM + gn) = v;
    }
    __syncthreads();  // keep waves in lockstep before region reuse (cheap, 4x)
  }
}

// ---------------------------------------------------------------------------
// Fallback (only if workspace is too small): correct but slow fp32 path.
// ---------------------------------------------------------------------------
__global__ __launch_bounds__(256) void fallback_kernel(
    const float* __restrict__ x, const float* __restrict__ w_dw,
    const float* __restrict__ b_dw, const float* __restrict__ w_pw,
    const float* __restrict__ b_pw, float* __restrict__ out) {
  __shared__ float ys[D_DIM];
  const int m = blockIdx.x;
  const int l = m & (L_SEQ - 1);
  const int t = threadIdx.x;
  const float* xr = x + (size_t)m * D_DIM;
#pragma unroll
  for (int c = 0; c < 4; ++c) {
    int d = t + c * 256;
    float a = fmaf(xr[d], w_dw[d * 3 + 2], b_dw[d]);
    if (l >= 1) a = fmaf(xr[d - D_DIM], w_dw[d * 3 + 1], a);
    if (l >= 2) a = fmaf(xr[d - 2 * D_DIM], w_dw[d * 3 + 0], a);
    ys[d] = a;
  }
  __syncthreads();
#pragma unroll
  for (int c = 0; c < 4; ++c) {
    int e = t + c * 256;
    const float* wr = w_pw + (size_t)e * D_DIM;
    float a = b_pw[e];
    for (int d = 0; d < D_DIM; ++d) a = fmaf(ys[d], wr[d], a);
    out[(size_t)m * D_DIM + e] = a;
  }
}

extern "C" void kernel_launch(void* const* d_in, const int* in_sizes, int n_in,
                              void* d_out, int out_size, void* d_ws, size_t ws_size,
                              hipStream_t stream) {
  (void)in_sizes; (void)n_in; (void)out_size;
  const float* x    = (const float*)d_in[0];
  const float* w_dw = (const float*)d_in[1];
  const float* b_dw = (const float*)d_in[2];
  const float* w_pw = (const float*)d_in[3];
  const float* b_pw = (const float*)d_in[4];
  float* out = (float*)d_out;

  const size_t y_elems = (size_t)M_TOT * D_DIM;          // 16M bf16 = 32 MB
  const size_t w_elems = (size_t)D_DIM * D_DIM;          // 1M bf16  =  2 MB
  const size_t need = (y_elems + w_elems) * sizeof(bf16);

  if (ws_size >= need) {
    bf16* y    = (bf16*)d_ws;
    bf16* wpwb = (bf16*)d_ws + y_elems;
    dw_bf16_kernel<<<B_SZ * (L_SEQ / 16), 256, 0, stream>>>(x, w_dw, b_dw, y);
    cvt_bf16_kernel<<<(D_DIM * D_DIM / 8) / 256, 256, 0, stream>>>(w_pw, wpwb);
    dim3 grid(M_TOT / BM, D_DIM / BN);
    gemm_bt_kernel<<<grid, 256, 0, stream>>>(y, wpwb, b_pw, out);
  } else {
    fallback_kernel<<<M_TOT, 256, 0, stream>>>(x, w_dw, b_dw, w_pw, b_pw, out);
  }
}